// Round 23
// baseline (111.938 us; speedup 1.0000x reference)
//
#include <hip/hip_runtime.h>
#include <hip/hip_bf16.h>
#include <hip/hip_fp8.h>

#define CC 256
#define DD 64
#define PP 18
#define ROWS 32768
#define EPSF 1e-5f

typedef __attribute__((ext_vector_type(8))) short bf16x8;
typedef __attribute__((ext_vector_type(4))) short s16x4;
typedef __attribute__((ext_vector_type(4))) float f32x4;
typedef __attribute__((ext_vector_type(8))) int i32x8;

// ---------------------------------------------------------------------------
// Merged weight prep (one dispatch, 768 blocks):
//  b <  256 : Wq/Wk/Wv/Wo -> 16x16 MFMA B-fragment order (bf16)
//  b <  512 : W1 -> MX-fp8 fragment pack (16x16x128): KB=2 blocks
//  b <  768 : W2 -> MX-fp8 fragment pack (16x16x128): KB=8 blocks
__global__ __launch_bounds__(256) void k_prep(
    const float* __restrict__ Wq, const float* __restrict__ Wk,
    const float* __restrict__ Wv, const float* __restrict__ Wo,
    const float* __restrict__ W1, const float* __restrict__ W2,
    __hip_bfloat16* __restrict__ WqP, __hip_bfloat16* __restrict__ WkP,
    __hip_bfloat16* __restrict__ WvP, __hip_bfloat16* __restrict__ WoP,
    unsigned char* __restrict__ W1P8, unsigned char* __restrict__ W2P8) {
    const int b = blockIdx.x, t = threadIdx.x;
    if (b < 256) {
        int i = b * 256 + t;
        const float* src; __hip_bfloat16* dst; int K, N, j;
        if (i < 16384)      { src = Wq; dst = WqP; K = 256; N = 64;  j = i; }
        else if (i < 32768) { src = Wk; dst = WkP; K = 256; N = 64;  j = i - 16384; }
        else if (i < 49152) { src = Wv; dst = WvP; K = 256; N = 64;  j = i - 32768; }
        else                { src = Wo; dst = WoP; K = 64;  N = 256; j = i - 49152; }
        int e = j & 7, l = (j >> 3) & 63, rest = j >> 9;
        int KS = K >> 5;
        int ks = rest % KS, nt = rest / KS;
        int row = ks * 32 + (l >> 4) * 8 + e;
        int col = nt * 16 + (l & 15);
        dst[j] = __float2bfloat16(src[(long)row * N + col]);
        return;
    }
    if (b < 512) {
        int j0 = (b - 256) * 1024 + t * 4;
#pragma unroll
        for (int q = 0; q < 4; ++q) {
            int jj = j0 + q;
            int e = jj & 31, ll = (jj >> 5) & 63, rest = jj >> 11;
            int kb = rest & 1, nt = rest >> 1;
            int row = kb * 128 + (ll >> 4) * 32 + e;
            int col = nt * 16 + (ll & 15);
            __hip_fp8_e4m3 q8(W1[(long)row * 1024 + col]);
            W1P8[jj] = q8.__x;
        }
        return;
    }
    {
        int j0 = (b - 512) * 1024 + t * 4;
#pragma unroll
        for (int q = 0; q < 4; ++q) {
            int jj = j0 + q;
            int e = jj & 31, ll = (jj >> 5) & 63, rest = jj >> 11;
            int kb = rest & 7, nt = rest >> 3;
            int row = kb * 128 + (ll >> 4) * 32 + e;
            int col = nt * 16 + (ll & 15);
            __hip_fp8_e4m3 q8(W2[(long)row * 256 + col]);
            W2P8[jj] = q8.__x;
        }
    }
}

// ---------------------------------------------------------------------------
// Fused QKV. 32 rows/block, 4 waves, 16x16 MFMA, A-frags hoisted.
__global__ __launch_bounds__(256) void k_qkv(
    const float4* __restrict__ X4, const float4* __restrict__ pe4,
    const __hip_bfloat16* __restrict__ WqP, const __hip_bfloat16* __restrict__ WkP,
    const __hip_bfloat16* __restrict__ WvP,
    const float* __restrict__ bq, const float* __restrict__ bk,
    const float* __restrict__ bv,
    __hip_bfloat16* __restrict__ Xpb,
    __hip_bfloat16* __restrict__ Qb, __hip_bfloat16* __restrict__ Kb,
    __hip_bfloat16* __restrict__ Vb) {
    __shared__ short Xs[32 * 256];      // 16 KB, swizzled
    const int t = threadIdx.x, w = t >> 6, l = t & 63;
    const int l15 = l & 15, lh = l >> 4;
    const int row0 = blockIdx.x * 32;

    for (int j = t; j < 2048; j += 256) {
        int r = j >> 6, c4 = j & 63;
        long g = row0 + r;
        float4 a = X4[(g << 6) + c4];
        float4 p = pe4[(long)((g & 16383) << 6) + c4];
        union { s16x4 v; __hip_bfloat16 h[4]; } u;
        u.h[0] = __float2bfloat16(a.x + p.x);
        u.h[1] = __float2bfloat16(a.y + p.y);
        u.h[2] = __float2bfloat16(a.z + p.z);
        u.h[3] = __float2bfloat16(a.w + p.w);
        int db = (r << 9) + (c4 << 3);
        db ^= (r & 7) << 4;
        *(s16x4*)((char*)Xs + db) = u.v;
        *(s16x4*)((char*)Xpb + (g << 9) + (c4 << 3)) = u.v;
    }
    __syncthreads();

    bf16x8 af[2][8];
#pragma unroll
    for (int ri = 0; ri < 2; ++ri)
#pragma unroll
        for (int ks = 0; ks < 8; ++ks) {
            int r = ri * 16 + l15;
            int db = (r << 9) + ks * 64 + lh * 16;
            db ^= (r & 7) << 4;
            af[ri][ks] = *(const bf16x8*)((const char*)Xs + db);
        }

    f32x4 acc[3][2];
#pragma unroll
    for (int j = 0; j < 3; ++j)
#pragma unroll
        for (int ri = 0; ri < 2; ++ri) acc[j][ri] = (f32x4)(0.f);

#pragma unroll
    for (int ks = 0; ks < 8; ++ks)
#pragma unroll
        for (int j = 0; j < 3; ++j) {
            int nt = w * 3 + j;
            const __hip_bfloat16* WP = (nt < 4) ? WqP : ((nt < 8) ? WkP : WvP);
            int ntl = nt & 3;
            bf16x8 b = *(const bf16x8*)(WP + (long)(((ntl * 8 + ks) << 6) + l) * 8);
#pragma unroll
            for (int ri = 0; ri < 2; ++ri)
                acc[j][ri] = __builtin_amdgcn_mfma_f32_16x16x32_bf16(
                    af[ri][ks], b, acc[j][ri], 0, 0, 0);
        }

#pragma unroll
    for (int j = 0; j < 3; ++j) {
        int nt = w * 3 + j;
        __hip_bfloat16* OP = (nt < 4) ? Qb : ((nt < 8) ? Kb : Vb);
        const float* BP = (nt < 4) ? bq : ((nt < 8) ? bk : bv);
        int col = (nt & 3) * 16 + l15;
        float bias = BP[col];
#pragma unroll
        for (int ri = 0; ri < 2; ++ri)
#pragma unroll
            for (int rg = 0; rg < 4; ++rg) {
                long row = row0 + ri * 16 + lh * 4 + rg;
                OP[row * DD + col] = __float2bfloat16(acc[j][ri][rg] + bias);
            }
    }
}

// ---------------------------------------------------------------------------
// Gather-attention v3, wave-parallel with grouped PV. One wave per token.
__global__ __launch_bounds__(256) void k_attn(const __hip_bfloat16* __restrict__ Q,
                                              const __hip_bfloat16* __restrict__ K,
                                              const __hip_bfloat16* __restrict__ V,
                                              const int* __restrict__ sel,
                                              __hip_bfloat16* __restrict__ ctx,
                                              float* __restrict__ attn_out) {
    const int wave  = threadIdx.x >> 6;
    const int lane  = threadIdx.x & 63;
    const int token = blockIdx.x * 4 + wave;
    const int b     = token >> 14;
    const int g = lane >> 3, s = lane & 7;

    const int* selp = sel + (long)token * PP;
    int sel_l = (lane < PP) ? selp[lane] : 0;

    float qf[8];
    {
        uint4 qv = *(const uint4*)(Q + (long)token * DD + s * 8);
        qf[0] = __uint_as_float(qv.x << 16);
        qf[1] = __uint_as_float(qv.x & 0xffff0000u);
        qf[2] = __uint_as_float(qv.y << 16);
        qf[3] = __uint_as_float(qv.y & 0xffff0000u);
        qf[4] = __uint_as_float(qv.z << 16);
        qf[5] = __uint_as_float(qv.z & 0xffff0000u);
        qf[6] = __uint_as_float(qv.w << 16);
        qf[7] = __uint_as_float(qv.w & 0xffff0000u);
    }

    const __hip_bfloat16* Kbase = K + (((long)b << 14) * DD);
    float sc[3];
    int idxs[3];
#pragma unroll
    for (int i = 0; i < 3; ++i) {
        int r = i * 8 + g;
        idxs[i] = __shfl(sel_l, r);
        uint4 kv = *(const uint4*)(Kbase + (long)idxs[i] * DD + s * 8);
        float part;
        part = qf[0] * __uint_as_float(kv.x << 16);
        part = fmaf(qf[1], __uint_as_float(kv.x & 0xffff0000u), part);
        part = fmaf(qf[2], __uint_as_float(kv.y << 16), part);
        part = fmaf(qf[3], __uint_as_float(kv.y & 0xffff0000u), part);
        part = fmaf(qf[4], __uint_as_float(kv.z << 16), part);
        part = fmaf(qf[5], __uint_as_float(kv.z & 0xffff0000u), part);
        part = fmaf(qf[6], __uint_as_float(kv.w << 16), part);
        part = fmaf(qf[7], __uint_as_float(kv.w & 0xffff0000u), part);
        part += __shfl_xor(part, 1);
        part += __shfl_xor(part, 2);
        part += __shfl_xor(part, 4);
        sc[i] = (r < PP) ? part * 0.125f : -1e30f;
    }

    float m = fmaxf(fmaxf(sc[0], sc[1]), sc[2]);
    m = fmaxf(m, __shfl_xor(m, 8));
    m = fmaxf(m, __shfl_xor(m, 16));
    m = fmaxf(m, __shfl_xor(m, 32));
    const float L2E = 1.4426950408889634f;
    float e0 = exp2f((sc[0] - m) * L2E);
    float e1 = exp2f((sc[1] - m) * L2E);
    float e2 = exp2f((sc[2] - m) * L2E);
    float dsum = e0 + e1 + e2;
    dsum += __shfl_xor(dsum, 8);
    dsum += __shfl_xor(dsum, 16);
    dsum += __shfl_xor(dsum, 32);
    float inv = 1.f / dsum;

    {
        int srcl = (lane & 7) << 3;
        float b0 = __shfl(e0, srcl);
        float b1 = __shfl(e1, srcl);
        float b2 = __shfl(e2, srcl);
        if (lane < PP) {
            float ev = (lane < 8) ? b0 : ((lane < 16) ? b1 : b2);
            attn_out[(long)token * PP + lane] = ev * inv;
        }
    }

    const __hip_bfloat16* Vbase = V + (((long)b << 14) * DD);
    float ca[8];
#pragma unroll
    for (int j = 0; j < 8; ++j) ca[j] = 0.f;
    float ev3[3] = {e0, e1, e2};
#pragma unroll
    for (int i = 0; i < 3; ++i) {
        uint4 vv = *(const uint4*)(Vbase + (long)idxs[i] * DD + s * 8);
        float e = ev3[i];
        ca[0] = fmaf(e, __uint_as_float(vv.x << 16), ca[0]);
        ca[1] = fmaf(e, __uint_as_float(vv.x & 0xffff0000u), ca[1]);
        ca[2] = fmaf(e, __uint_as_float(vv.y << 16), ca[2]);
        ca[3] = fmaf(e, __uint_as_float(vv.y & 0xffff0000u), ca[3]);
        ca[4] = fmaf(e, __uint_as_float(vv.z << 16), ca[4]);
        ca[5] = fmaf(e, __uint_as_float(vv.z & 0xffff0000u), ca[5]);
        ca[6] = fmaf(e, __uint_as_float(vv.w << 16), ca[6]);
        ca[7] = fmaf(e, __uint_as_float(vv.w & 0xffff0000u), ca[7]);
    }
#pragma unroll
    for (int o = 8; o <= 32; o <<= 1)
#pragma unroll
        for (int j = 0; j < 8; ++j) ca[j] += __shfl_xor(ca[j], o);
    if (g == 0) {
        union { bf16x8 v; __hip_bfloat16 h[8]; } u;
#pragma unroll
        for (int j = 0; j < 8; ++j) u.h[j] = __float2bfloat16(ca[j] * inv);
        *(bf16x8*)(ctx + (long)token * DD + s * 8) = u.v;
    }
}

// ---------------------------------------------------------------------------
// proj + LN1: Xn = LN(Xpb + ctx@Wo + bo)*g1 + be1 -> bf16 (in-place on Xpb)
// AND fp8 e4m3 copy (Xn8, consumed by MX gemm1).
__global__ __launch_bounds__(256) void k_projln(
    const __hip_bfloat16* __restrict__ ctx, const __hip_bfloat16* __restrict__ WoP,
    const float* __restrict__ bo, const float* __restrict__ g1,
    const float* __restrict__ be1,
    const __hip_bfloat16* __restrict__ Xpb, __hip_bfloat16* __restrict__ Xnb,
    unsigned char* __restrict__ Xn8) {
    __shared__ short Cs[32 * 64];       // 4 KB, swizzled
    __shared__ float red[2][32][2];
    __shared__ float mrs[32][2];
    const int t = threadIdx.x, w = t >> 6, l = t & 63;
    const int l15 = l & 15, lh = l >> 4;
    const int row0 = blockIdx.x * 32;

    {
        int r = t >> 3, ch = t & 7;
        int db = (r << 7) + (ch << 4);
        db ^= (r & 7) << 4;
        *(bf16x8*)((char*)Cs + db) = *(const bf16x8*)(ctx + (long)(row0 + r) * DD + ch * 8);
    }
    __syncthreads();

    const int ri = w & 1, nh = w >> 1;

    bf16x8 af[2];
#pragma unroll
    for (int ks = 0; ks < 2; ++ks) {
        int r = ri * 16 + l15;
        int db = (r << 7) + ks * 64 + lh * 16;
        db ^= (r & 7) << 4;
        af[ks] = *(const bf16x8*)((const char*)Cs + db);
    }

    f32x4 acc[8];
#pragma unroll
    for (int j = 0; j < 8; ++j) acc[j] = (f32x4)(0.f);

#pragma unroll
    for (int ks = 0; ks < 2; ++ks)
#pragma unroll
        for (int j = 0; j < 8; ++j) {
            int nt = nh * 8 + j;
            bf16x8 b = *(const bf16x8*)(WoP + (long)(((nt * 2 + ks) << 6) + l) * 8);
            acc[j] = __builtin_amdgcn_mfma_f32_16x16x32_bf16(af[ks], b, acc[j], 0, 0, 0);
        }

    float bov[8], g1v[8], be1v[8];
#pragma unroll
    for (int j = 0; j < 8; ++j) {
        int col = (nh * 8 + j) * 16 + l15;
        bov[j] = bo[col]; g1v[j] = g1[col]; be1v[j] = be1[col];
    }

    float xv[4][8];
#pragma unroll
    for (int rg = 0; rg < 4; ++rg) {
        long grow = row0 + ri * 16 + lh * 4 + rg;
        float s = 0.f, q = 0.f;
#pragma unroll
        for (int j = 0; j < 8; ++j) {
            float v = acc[j][rg] + bov[j] +
                      __bfloat162float(Xpb[grow * CC + (nh * 8 + j) * 16 + l15]);
            xv[rg][j] = v; s += v; q += v * v;
        }
#pragma unroll
        for (int o = 8; o > 0; o >>= 1) { s += __shfl_xor(s, o); q += __shfl_xor(q, o); }
        if (l15 == 0) {
            int rl = ri * 16 + lh * 4 + rg;
            red[nh][rl][0] = s; red[nh][rl][1] = q;
        }
    }
    __syncthreads();
    if (t < 32) {
        float S = red[0][t][0] + red[1][t][0];
        float Q = red[0][t][1] + red[1][t][1];
        float mu = S * (1.f / CC);
        float var = Q * (1.f / CC) - mu * mu;
        mrs[t][0] = mu; mrs[t][1] = rsqrtf(var + EPSF);
    }
    __syncthreads();
#pragma unroll
    for (int rg = 0; rg < 4; ++rg) {
        int rl = ri * 16 + lh * 4 + rg;
        long grow = row0 + rl;
        float mu = mrs[rl][0], rs = mrs[rl][1];
#pragma unroll
        for (int j = 0; j < 8; ++j) {
            int col = (nh * 8 + j) * 16 + l15;
            float vout = (xv[rg][j] - mu) * rs * g1v[j] + be1v[j];
            Xnb[grow * CC + col] = __float2bfloat16(vout);
            __hip_fp8_e4m3 q8(vout);
            Xn8[grow * CC + col] = q8.__x;
        }
    }
}

// ---------------------------------------------------------------------------
// GEMM1 MX-fp8: H8 = fp8(relu(Xn8 @ W1 + b1)), 128x128 tile, 4 waves,
// K=256 via 2 x mfma_scale_f32_16x16x128_f8f6f4 (unit scales).
// Epilogue v2: repack through LDS, fully coalesced 16B/lane H8 stores
// (fixes 2.3x HBM write amplification from scalar byte stores).
template<int GRL2, int CTL2>
__global__ __launch_bounds__(256) void k_gemm1mx(
    const unsigned char* __restrict__ X8,    // [32768][256] fp8 e4m3
    const unsigned char* __restrict__ W1P8,  // MX frag pack, 256 KB
    const float* __restrict__ bias,          // b1 [1024]
    unsigned char* __restrict__ H8) {        // [32768][1024] fp8
    __shared__ unsigned char Xs[128 * 256];  // 32 KB; also reused as Ht[128][128]

    const int t = threadIdx.x, w = t >> 6, l = t & 63;
    const int l15 = l & 15, lh = l >> 4;
    const int bid = blockIdx.x;
    const int wi = bid & ((1 << (GRL2 + CTL2)) - 1);
    const int rt = ((bid >> (GRL2 + CTL2)) << GRL2) | (wi & ((1 << GRL2) - 1));
    const int ct = wi >> GRL2;
    const int row0 = rt * 128, n0 = ct * 128;
    const int wr = w & 1, wc = w >> 1;

    for (int i = t; i < 2048; i += 256) {
        int r = i >> 4, c = i & 15;
        int pc = c ^ (r & 7);
        *(int4*)(Xs + r * 256 + pc * 16) =
            *(const int4*)(X8 + (long)(row0 + r) * 256 + c * 16);
    }
    __syncthreads();

    i32x8 afr[4][2];
#pragma unroll
    for (int f = 0; f < 4; ++f) {
        int row = wr * 64 + f * 16 + l15;
        int sw = row & 7;
#pragma unroll
        for (int kb = 0; kb < 2; ++kb) {
            int c0 = kb * 8 + lh * 2;
            int4 lo = *(const int4*)(Xs + row * 256 + (c0 ^ sw) * 16);
            int4 hi = *(const int4*)(Xs + row * 256 + ((c0 + 1) ^ sw) * 16);
            afr[f][kb][0] = lo.x; afr[f][kb][1] = lo.y;
            afr[f][kb][2] = lo.z; afr[f][kb][3] = lo.w;
            afr[f][kb][4] = hi.x; afr[f][kb][5] = hi.y;
            afr[f][kb][6] = hi.z; afr[f][kb][7] = hi.w;
        }
    }

    f32x4 acc[4][4];
#pragma unroll
    for (int i = 0; i < 4; ++i)
#pragma unroll
        for (int j = 0; j < 4; ++j) acc[i][j] = (f32x4)(0.f);

#pragma unroll
    for (int kb = 0; kb < 2; ++kb)
#pragma unroll
        for (int nf = 0; nf < 4; ++nf) {
            int nt = (n0 >> 4) + wc * 4 + nf;
            const unsigned char* bp = W1P8 + ((long)((nt * 2 + kb) * 64 + l)) * 32;
            int4 lo = *(const int4*)(bp);
            int4 hi = *(const int4*)(bp + 16);
            i32x8 bfr;
            bfr[0] = lo.x; bfr[1] = lo.y; bfr[2] = lo.z; bfr[3] = lo.w;
            bfr[4] = hi.x; bfr[5] = hi.y; bfr[6] = hi.z; bfr[7] = hi.w;
#pragma unroll
            for (int f = 0; f < 4; ++f)
                acc[f][nf] = __builtin_amdgcn_mfma_scale_f32_16x16x128_f8f6f4(
                    afr[f][kb], bfr, acc[f][nf], 0, 0, 0, 127, 0, 127);
        }

    // ---- epilogue: quantize -> LDS tile -> coalesced 16B stores ----
    __syncthreads();                     // all waves done reading Xs A-frags
    unsigned char* Ht = Xs;              // [128][128] fp8 tile (16 KB)
#pragma unroll
    for (int nf = 0; nf < 4; ++nf) {
        int coll = wc * 64 + nf * 16 + l15;
        float bv = bias[n0 + coll];
#pragma unroll
        for (int f = 0; f < 4; ++f)
#pragma unroll
            for (int rg = 0; rg < 4; ++rg) {
                int row = wr * 64 + f * 16 + lh * 4 + rg;
                __hip_fp8_e4m3 q8(fmaxf(acc[f][nf][rg] + bv, 0.f));
                Ht[row * 128 + coll] = q8.__x;
            }
    }
    __syncthreads();
    // 128 rows x 8 chunks of 16B = 1024 chunks; 4 per thread; 8 lanes = 128B
    // contiguous per H8 row -> full HBM sectors.
#pragma unroll
    for (int i = 0; i < 4; ++i) {
        int idx = t + i * 256;
        int r = idx >> 3, c = idx & 7;
        *(int4*)(H8 + (long)(row0 + r) * 1024 + n0 + c * 16) =
            *(const int4*)(Ht + r * 128 + c * 16);
    }
}

// ---------------------------------------------------------------------------
// GEMM2 MX-fp8 + residual + LN2: out = LN(H8 @ W2 + b2 + Res)*g2 + be2.
// 64 rows x 256 cols, 512 thr, 8 waves. Whole 64x1024 fp8 A-tile staged once
// in 64 KB LDS (chunk-XOR swizzle); 64 mfma_scale per wave; no mid-loop bars.
__global__ __launch_bounds__(512) void k_gemm2lnmx(
    const unsigned char* __restrict__ H8,    // [32768][1024] fp8
    const unsigned char* __restrict__ W2P8,  // MX frag pack, 256 KB
    const float* __restrict__ b2,
    const __hip_bfloat16* __restrict__ Res,  // Xn bf16 [32768][256]
    const float* __restrict__ g2, const float* __restrict__ be2,
    float* __restrict__ out) {
    __shared__ unsigned char Hs[64 * 1024];  // 64 KB
    __shared__ float red[4][64][2];          // 2 KB
    __shared__ float mrs[64][2];

    const int t = threadIdx.x, w = t >> 6, l = t & 63;
    const int l15 = l & 15, lh = l >> 4;
    const int wr = w >> 2, wc = w & 3;
    const int row0 = blockIdx.x * 64;

    {
        int r = t >> 3, sw = r & 7;
        const unsigned char* src = H8 + (long)(row0 + r) * 1024;
        unsigned char* dst = Hs + r * 1024;
#pragma unroll
        for (int j = 0; j < 8; ++j) {
            int c = (t & 7) + j * 8;
            *(int4*)(dst + (c ^ sw) * 16) = *(const int4*)(src + c * 16);
        }
    }
    __syncthreads();

    f32x4 acc[2][4];
#pragma unroll
    for (int i = 0; i < 2; ++i)
#pragma unroll
        for (int j = 0; j < 4; ++j) acc[i][j] = (f32x4)(0.f);

#pragma unroll 2
    for (int kb = 0; kb < 8; ++kb) {
        i32x8 afr[2];
#pragma unroll
        for (int f = 0; f < 2; ++f) {
            int row = wr * 32 + f * 16 + l15;
            int sw = row & 7;
            int c0 = kb * 8 + lh * 2;
            const unsigned char* hp = Hs + row * 1024;
            int4 lo = *(const int4*)(hp + ((c0 ^ sw) << 4));
            int4 hi = *(const int4*)(hp + (((c0 + 1) ^ sw) << 4));
            afr[f][0] = lo.x; afr[f][1] = lo.y; afr[f][2] = lo.z; afr[f][3] = lo.w;
            afr[f][4] = hi.x; afr[f][5] = hi.y; afr[f][6] = hi.z; afr[f][7] = hi.w;
        }
#pragma unroll
        for (int nf = 0; nf < 4; ++nf) {
            int nt = wc * 4 + nf;
            const unsigned char* bp = W2P8 + ((long)((nt * 8 + kb) * 64 + l)) * 32;
            int4 lo = *(const int4*)(bp);
            int4 hi = *(const int4*)(bp + 16);
            i32x8 bfr;
            bfr[0] = lo.x; bfr[1] = lo.y; bfr[2] = lo.z; bfr[3] = lo.w;
            bfr[4] = hi.x; bfr[5] = hi.y; bfr[6] = hi.z; bfr[7] = hi.w;
#pragma unroll
            for (int f = 0; f < 2; ++f)
                acc[f][nf] = __builtin_amdgcn_mfma_scale_f32_16x16x128_f8f6f4(
                    afr[f], bfr, acc[f][nf], 0, 0, 0, 127, 0, 127);
        }
    }

    float b2v[4], g2v[4], be2v[4];
#pragma unroll
    for (int fc = 0; fc < 4; ++fc) {
        int col = wc * 64 + fc * 16 + l15;
        b2v[fc] = b2[col]; g2v[fc] = g2[col]; be2v[fc] = be2[col];
    }
#pragma unroll
    for (int fr = 0; fr < 2; ++fr)
#pragma unroll
        for (int rg = 0; rg < 4; ++rg) {
            int row = wr * 32 + fr * 16 + lh * 4 + rg;
            float s = 0.f, q = 0.f;
#pragma unroll
            for (int fc = 0; fc < 4; ++fc) {
                long gi = (long)(row0 + row) * CC + wc * 64 + fc * 16 + l15;
                float v = acc[fr][fc][rg] + b2v[fc] + __bfloat162float(Res[gi]);
                acc[fr][fc][rg] = v;
                s += v; q += v * v;
            }
#pragma unroll
            for (int o = 8; o > 0; o >>= 1) {
                s += __shfl_xor(s, o); q += __shfl_xor(q, o);
            }
            if (l15 == 0) { red[wc][row][0] = s; red[wc][row][1] = q; }
        }
    __syncthreads();
    if (t < 64) {
        float S = 0.f, Q = 0.f;
#pragma unroll
        for (int ww = 0; ww < 4; ++ww) { S += red[ww][t][0]; Q += red[ww][t][1]; }
        float mu = S * (1.f / CC);
        float var = Q * (1.f / CC) - mu * mu;
        mrs[t][0] = mu; mrs[t][1] = rsqrtf(var + EPSF);
    }
    __syncthreads();
#pragma unroll
    for (int fr = 0; fr < 2; ++fr)
#pragma unroll
        for (int rg = 0; rg < 4; ++rg) {
            int row = wr * 32 + fr * 16 + lh * 4 + rg;
            float mu = mrs[row][0], rs = mrs[row][1];
#pragma unroll
            for (int fc = 0; fc < 4; ++fc) {
                long gi = (long)(row0 + row) * CC + wc * 64 + fc * 16 + l15;
                out[gi] = (acc[fr][fc][rg] - mu) * rs * g2v[fc] + be2v[fc];
            }
        }
}

// ---------------------------------------------------------------------------
extern "C" void kernel_launch(void* const* d_in, const int* in_sizes, int n_in,
                              void* d_out, int out_size, void* d_ws, size_t ws_size,
                              hipStream_t stream) {
    const float* X   = (const float*)d_in[0];
    const int*   sel = (const int*)d_in[1];
    const float* pe  = (const float*)d_in[3];
    const float* Wq  = (const float*)d_in[4];
    const float* bq  = (const float*)d_in[5];
    const float* Wk  = (const float*)d_in[6];
    const float* bk  = (const float*)d_in[7];
    const float* Wv  = (const float*)d_in[8];
    const float* bv  = (const float*)d_in[9];
    const float* Wo  = (const float*)d_in[10];
    const float* bo  = (const float*)d_in[11];
    const float* W1  = (const float*)d_in[12];
    const float* b1  = (const float*)d_in[13];
    const float* W2  = (const float*)d_in[14];
    const float* b2  = (const float*)d_in[15];
    const float* g1  = (const float*)d_in[16];
    const float* be1 = (const float*)d_in[17];
    const float* g2  = (const float*)d_in[18];
    const float* be2 = (const float*)d_in[19];

    float* out = (float*)d_out;
    char*  ws  = (char*)d_ws;       // ws_size ~= 256 MiB

    __hip_bfloat16* Xpb = (__hip_bfloat16*)(ws);                  // 16 MB (Xp->Xn in place)
    __hip_bfloat16* Qb  = (__hip_bfloat16*)(ws + (16 << 20));     // 4 MB
    __hip_bfloat16* Kb  = (__hip_bfloat16*)(ws + (20 << 20));     // 4 MB
    __hip_bfloat16* Vb  = (__hip_bfloat16*)(ws + (24 << 20));     // 4 MB
    __hip_bfloat16* ctxb= (__hip_bfloat16*)(ws + (28 << 20));     // 4 MB
    unsigned char*  H8  = (unsigned char*)(ws + (40 << 20));      // 32 MB fp8 H
    unsigned char*  Xn8 = (unsigned char*)(ws + (88 << 20));      // 8 MB fp8 Xn
    __hip_bfloat16* WqP = (__hip_bfloat16*)(ws + (96 << 20));     // 32 KB
    __hip_bfloat16* WkP = WqP + 16384;
    __hip_bfloat16* WvP = WkP + 16384;
    __hip_bfloat16* WoP = WvP + 16384;                            // 32 KB
    unsigned char*  W1P8= (unsigned char*)(WoP + 16384);          // 256 KB MX fp8
    unsigned char*  W2P8= W1P8 + 262144;                          // 256 KB MX fp8
    float* attn_out = out + (long)ROWS * CC;

    k_prep<<<768, 256, 0, stream>>>(Wq, Wk, Wv, Wo, W1, W2,
                                    WqP, WkP, WvP, WoP, W1P8, W2P8);

    k_qkv<<<ROWS / 32, 256, 0, stream>>>((const float4*)X, (const float4*)pe,
                                         WqP, WkP, WvP, bq, bk, bv,
                                         Xpb, Qb, Kb, Vb);

    k_attn<<<ROWS / 4, 256, 0, stream>>>(Qb, Kb, Vb, sel, ctxb, attn_out);

    k_projln<<<ROWS / 32, 256, 0, stream>>>(ctxb, WoP, bo, g1, be1, Xpb, Xpb, Xn8);

    // FFN: H8 = fp8(relu(Xn @ W1 + b1))  [MX-fp8, coalesced store epilogue]
    k_gemm1mx<2, 3><<<2048, 256, 0, stream>>>(Xn8, W1P8, b1, H8);
    // out = LN(H8 @ W2 + b2 + Xn) * g2 + be2  [MX-fp8, 64x256 tiles]
    k_gemm2lnmx<<<512, 512, 0, stream>>>(H8, W2P8, b2, Xpb, g2, be2, out);
}

// Round 24
// 109.296 us; speedup vs baseline: 1.0242x; 1.0242x over previous
//
#include <hip/hip_runtime.h>
#include <hip/hip_bf16.h>
#include <hip/hip_fp8.h>

#define CC 256
#define DD 64
#define PP 18
#define ROWS 32768
#define EPSF 1e-5f

typedef __attribute__((ext_vector_type(8))) short bf16x8;
typedef __attribute__((ext_vector_type(4))) short s16x4;
typedef __attribute__((ext_vector_type(4))) float f32x4;
typedef __attribute__((ext_vector_type(8))) int i32x8;

#define WAIT_VM(N) do {                                       \
    asm volatile("s_waitcnt vmcnt(" #N ")" ::: "memory");     \
    __builtin_amdgcn_s_barrier();                             \
    __builtin_amdgcn_sched_barrier(0);                        \
} while (0)

// global -> LDS direct DMA, 16 bytes/lane.
__device__ __forceinline__ void gl_lds16(const void* g, void* l) {
    __builtin_amdgcn_global_load_lds(
        (const __attribute__((address_space(1))) unsigned int*)g,
        (__attribute__((address_space(3))) unsigned int*)l, 16, 0, 0);
}

// Inverse for 128-byte rows: p = r*128 + ((c*16) ^ ((r&7)<<4)).
__device__ __forceinline__ void inv_swz128(int p, int& r, int& c) {
    r = p >> 7;
    c = ((p >> 4) & 7) ^ (r & 7);
}

// ---------------------------------------------------------------------------
// Merged weight prep (one dispatch, 768 blocks):
//  b <  256 : Wq/Wk/Wv/Wo -> 16x16 MFMA B-fragment order (bf16)
//  b <  512 : W1 -> MX-fp8 fragment pack for mfma 16x16x128 f8f6f4
//  b <  768 : W2 [1024][256] -> W2T [256][1024] (tiled transpose, bf16)
__global__ __launch_bounds__(256) void k_prep(
    const float* __restrict__ Wq, const float* __restrict__ Wk,
    const float* __restrict__ Wv, const float* __restrict__ Wo,
    const float* __restrict__ W1, const float* __restrict__ W2,
    __hip_bfloat16* __restrict__ WqP, __hip_bfloat16* __restrict__ WkP,
    __hip_bfloat16* __restrict__ WvP, __hip_bfloat16* __restrict__ WoP,
    unsigned char* __restrict__ W1P8, __hip_bfloat16* __restrict__ W2T) {
    __shared__ float tile[32][33];
    const int b = blockIdx.x, t = threadIdx.x;
    if (b < 256) {
        int i = b * 256 + t;
        const float* src; __hip_bfloat16* dst; int K, N, j;
        if (i < 16384)      { src = Wq; dst = WqP; K = 256; N = 64;  j = i; }
        else if (i < 32768) { src = Wk; dst = WkP; K = 256; N = 64;  j = i - 16384; }
        else if (i < 49152) { src = Wv; dst = WvP; K = 256; N = 64;  j = i - 32768; }
        else                { src = Wo; dst = WoP; K = 64;  N = 256; j = i - 49152; }
        int e = j & 7, l = (j >> 3) & 63, rest = j >> 9;
        int KS = K >> 5;
        int ks = rest % KS, nt = rest / KS;
        int row = ks * 32 + (l >> 4) * 8 + e;
        int col = nt * 16 + (l & 15);
        dst[j] = __float2bfloat16(src[(long)row * N + col]);
        return;
    }
    if (b < 512) {
        // W1 MX-fp8 pack: 262144 bytes total, 4 bytes/thread
        int j0 = (b - 256) * 1024 + t * 4;
#pragma unroll
        for (int q = 0; q < 4; ++q) {
            int jj = j0 + q;
            int e = jj & 31, ll = (jj >> 5) & 63, rest = jj >> 11;
            int kb = rest & 1, nt = rest >> 1;
            int row = kb * 128 + (ll >> 4) * 32 + e;
            int col = nt * 16 + (ll & 15);
            __hip_fp8_e4m3 q8(W1[(long)row * 1024 + col]);
            W1P8[jj] = q8.__x;
        }
        return;
    }
    // W2 tiled transpose: 1024 x 256 -> [256][1024]
    {
        int bb = b - 512;
        int r0 = (bb >> 3) * 32, c0 = (bb & 7) * 32;
#pragma unroll
        for (int i = 0; i < 4; ++i) {
            int idx = t + i * 256;
            int r = idx >> 5, c = idx & 31;
            tile[r][c] = W2[(long)(r0 + r) * 256 + c0 + c];
        }
        __syncthreads();
#pragma unroll
        for (int i = 0; i < 4; ++i) {
            int idx = t + i * 256;
            int c2 = idx >> 5, r2 = idx & 31;
            W2T[(long)(c0 + c2) * 1024 + r0 + r2] = __float2bfloat16(tile[r2][c2]);
        }
    }
}

// ---------------------------------------------------------------------------
// Fused QKV. 32 rows/block, 4 waves, 16x16 MFMA, A-frags hoisted.
__global__ __launch_bounds__(256) void k_qkv(
    const float4* __restrict__ X4, const float4* __restrict__ pe4,
    const __hip_bfloat16* __restrict__ WqP, const __hip_bfloat16* __restrict__ WkP,
    const __hip_bfloat16* __restrict__ WvP,
    const float* __restrict__ bq, const float* __restrict__ bk,
    const float* __restrict__ bv,
    __hip_bfloat16* __restrict__ Xpb,
    __hip_bfloat16* __restrict__ Qb, __hip_bfloat16* __restrict__ Kb,
    __hip_bfloat16* __restrict__ Vb) {
    __shared__ short Xs[32 * 256];      // 16 KB, swizzled
    const int t = threadIdx.x, w = t >> 6, l = t & 63;
    const int l15 = l & 15, lh = l >> 4;
    const int row0 = blockIdx.x * 32;

    for (int j = t; j < 2048; j += 256) {
        int r = j >> 6, c4 = j & 63;
        long g = row0 + r;
        float4 a = X4[(g << 6) + c4];
        float4 p = pe4[(long)((g & 16383) << 6) + c4];
        union { s16x4 v; __hip_bfloat16 h[4]; } u;
        u.h[0] = __float2bfloat16(a.x + p.x);
        u.h[1] = __float2bfloat16(a.y + p.y);
        u.h[2] = __float2bfloat16(a.z + p.z);
        u.h[3] = __float2bfloat16(a.w + p.w);
        int db = (r << 9) + (c4 << 3);
        db ^= (r & 7) << 4;
        *(s16x4*)((char*)Xs + db) = u.v;
        *(s16x4*)((char*)Xpb + (g << 9) + (c4 << 3)) = u.v;
    }
    __syncthreads();

    bf16x8 af[2][8];
#pragma unroll
    for (int ri = 0; ri < 2; ++ri)
#pragma unroll
        for (int ks = 0; ks < 8; ++ks) {
            int r = ri * 16 + l15;
            int db = (r << 9) + ks * 64 + lh * 16;
            db ^= (r & 7) << 4;
            af[ri][ks] = *(const bf16x8*)((const char*)Xs + db);
        }

    f32x4 acc[3][2];
#pragma unroll
    for (int j = 0; j < 3; ++j)
#pragma unroll
        for (int ri = 0; ri < 2; ++ri) acc[j][ri] = (f32x4)(0.f);

#pragma unroll
    for (int ks = 0; ks < 8; ++ks)
#pragma unroll
        for (int j = 0; j < 3; ++j) {
            int nt = w * 3 + j;
            const __hip_bfloat16* WP = (nt < 4) ? WqP : ((nt < 8) ? WkP : WvP);
            int ntl = nt & 3;
            bf16x8 b = *(const bf16x8*)(WP + (long)(((ntl * 8 + ks) << 6) + l) * 8);
#pragma unroll
            for (int ri = 0; ri < 2; ++ri)
                acc[j][ri] = __builtin_amdgcn_mfma_f32_16x16x32_bf16(
                    af[ri][ks], b, acc[j][ri], 0, 0, 0);
        }

#pragma unroll
    for (int j = 0; j < 3; ++j) {
        int nt = w * 3 + j;
        __hip_bfloat16* OP = (nt < 4) ? Qb : ((nt < 8) ? Kb : Vb);
        const float* BP = (nt < 4) ? bq : ((nt < 8) ? bk : bv);
        int col = (nt & 3) * 16 + l15;
        float bias = BP[col];
#pragma unroll
        for (int ri = 0; ri < 2; ++ri)
#pragma unroll
            for (int rg = 0; rg < 4; ++rg) {
                long row = row0 + ri * 16 + lh * 4 + rg;
                OP[row * DD + col] = __float2bfloat16(acc[j][ri][rg] + bias);
            }
    }
}

// ---------------------------------------------------------------------------
// Gather-attention v3, wave-parallel with grouped PV. One wave per token.
__global__ __launch_bounds__(256) void k_attn(const __hip_bfloat16* __restrict__ Q,
                                              const __hip_bfloat16* __restrict__ K,
                                              const __hip_bfloat16* __restrict__ V,
                                              const int* __restrict__ sel,
                                              __hip_bfloat16* __restrict__ ctx,
                                              float* __restrict__ attn_out) {
    const int wave  = threadIdx.x >> 6;
    const int lane  = threadIdx.x & 63;
    const int token = blockIdx.x * 4 + wave;
    const int b     = token >> 14;
    const int g = lane >> 3, s = lane & 7;

    const int* selp = sel + (long)token * PP;
    int sel_l = (lane < PP) ? selp[lane] : 0;

    float qf[8];
    {
        uint4 qv = *(const uint4*)(Q + (long)token * DD + s * 8);
        qf[0] = __uint_as_float(qv.x << 16);
        qf[1] = __uint_as_float(qv.x & 0xffff0000u);
        qf[2] = __uint_as_float(qv.y << 16);
        qf[3] = __uint_as_float(qv.y & 0xffff0000u);
        qf[4] = __uint_as_float(qv.z << 16);
        qf[5] = __uint_as_float(qv.z & 0xffff0000u);
        qf[6] = __uint_as_float(qv.w << 16);
        qf[7] = __uint_as_float(qv.w & 0xffff0000u);
    }

    const __hip_bfloat16* Kbase = K + (((long)b << 14) * DD);
    float sc[3];
    int idxs[3];
#pragma unroll
    for (int i = 0; i < 3; ++i) {
        int r = i * 8 + g;
        idxs[i] = __shfl(sel_l, r);
        uint4 kv = *(const uint4*)(Kbase + (long)idxs[i] * DD + s * 8);
        float part;
        part = qf[0] * __uint_as_float(kv.x << 16);
        part = fmaf(qf[1], __uint_as_float(kv.x & 0xffff0000u), part);
        part = fmaf(qf[2], __uint_as_float(kv.y << 16), part);
        part = fmaf(qf[3], __uint_as_float(kv.y & 0xffff0000u), part);
        part = fmaf(qf[4], __uint_as_float(kv.z << 16), part);
        part = fmaf(qf[5], __uint_as_float(kv.z & 0xffff0000u), part);
        part = fmaf(qf[6], __uint_as_float(kv.w << 16), part);
        part = fmaf(qf[7], __uint_as_float(kv.w & 0xffff0000u), part);
        part += __shfl_xor(part, 1);
        part += __shfl_xor(part, 2);
        part += __shfl_xor(part, 4);
        sc[i] = (r < PP) ? part * 0.125f : -1e30f;
    }

    float m = fmaxf(fmaxf(sc[0], sc[1]), sc[2]);
    m = fmaxf(m, __shfl_xor(m, 8));
    m = fmaxf(m, __shfl_xor(m, 16));
    m = fmaxf(m, __shfl_xor(m, 32));
    const float L2E = 1.4426950408889634f;
    float e0 = exp2f((sc[0] - m) * L2E);
    float e1 = exp2f((sc[1] - m) * L2E);
    float e2 = exp2f((sc[2] - m) * L2E);
    float dsum = e0 + e1 + e2;
    dsum += __shfl_xor(dsum, 8);
    dsum += __shfl_xor(dsum, 16);
    dsum += __shfl_xor(dsum, 32);
    float inv = 1.f / dsum;

    {
        int srcl = (lane & 7) << 3;
        float b0 = __shfl(e0, srcl);
        float b1 = __shfl(e1, srcl);
        float b2 = __shfl(e2, srcl);
        if (lane < PP) {
            float ev = (lane < 8) ? b0 : ((lane < 16) ? b1 : b2);
            attn_out[(long)token * PP + lane] = ev * inv;
        }
    }

    const __hip_bfloat16* Vbase = V + (((long)b << 14) * DD);
    float ca[8];
#pragma unroll
    for (int j = 0; j < 8; ++j) ca[j] = 0.f;
    float ev3[3] = {e0, e1, e2};
#pragma unroll
    for (int i = 0; i < 3; ++i) {
        uint4 vv = *(const uint4*)(Vbase + (long)idxs[i] * DD + s * 8);
        float e = ev3[i];
        ca[0] = fmaf(e, __uint_as_float(vv.x << 16), ca[0]);
        ca[1] = fmaf(e, __uint_as_float(vv.x & 0xffff0000u), ca[1]);
        ca[2] = fmaf(e, __uint_as_float(vv.y << 16), ca[2]);
        ca[3] = fmaf(e, __uint_as_float(vv.y & 0xffff0000u), ca[3]);
        ca[4] = fmaf(e, __uint_as_float(vv.z << 16), ca[4]);
        ca[5] = fmaf(e, __uint_as_float(vv.z & 0xffff0000u), ca[5]);
        ca[6] = fmaf(e, __uint_as_float(vv.w << 16), ca[6]);
        ca[7] = fmaf(e, __uint_as_float(vv.w & 0xffff0000u), ca[7]);
    }
#pragma unroll
    for (int o = 8; o <= 32; o <<= 1)
#pragma unroll
        for (int j = 0; j < 8; ++j) ca[j] += __shfl_xor(ca[j], o);
    if (g == 0) {
        union { bf16x8 v; __hip_bfloat16 h[8]; } u;
#pragma unroll
        for (int j = 0; j < 8; ++j) u.h[j] = __float2bfloat16(ca[j] * inv);
        *(bf16x8*)(ctx + (long)token * DD + s * 8) = u.v;
    }
}

// ---------------------------------------------------------------------------
// proj + LN1: Xn = LN(Xpb + ctx@Wo + bo)*g1 + be1 -> bf16 (in-place on Xpb)
// AND fp8 e4m3 copy (Xn8, consumed by MX gemm1).
__global__ __launch_bounds__(256) void k_projln(
    const __hip_bfloat16* __restrict__ ctx, const __hip_bfloat16* __restrict__ WoP,
    const float* __restrict__ bo, const float* __restrict__ g1,
    const float* __restrict__ be1,
    const __hip_bfloat16* __restrict__ Xpb, __hip_bfloat16* __restrict__ Xnb,
    unsigned char* __restrict__ Xn8) {
    __shared__ short Cs[32 * 64];       // 4 KB, swizzled
    __shared__ float red[2][32][2];
    __shared__ float mrs[32][2];
    const int t = threadIdx.x, w = t >> 6, l = t & 63;
    const int l15 = l & 15, lh = l >> 4;
    const int row0 = blockIdx.x * 32;

    {
        int r = t >> 3, ch = t & 7;
        int db = (r << 7) + (ch << 4);
        db ^= (r & 7) << 4;
        *(bf16x8*)((char*)Cs + db) = *(const bf16x8*)(ctx + (long)(row0 + r) * DD + ch * 8);
    }
    __syncthreads();

    const int ri = w & 1, nh = w >> 1;

    bf16x8 af[2];
#pragma unroll
    for (int ks = 0; ks < 2; ++ks) {
        int r = ri * 16 + l15;
        int db = (r << 7) + ks * 64 + lh * 16;
        db ^= (r & 7) << 4;
        af[ks] = *(const bf16x8*)((const char*)Cs + db);
    }

    f32x4 acc[8];
#pragma unroll
    for (int j = 0; j < 8; ++j) acc[j] = (f32x4)(0.f);

#pragma unroll
    for (int ks = 0; ks < 2; ++ks)
#pragma unroll
        for (int j = 0; j < 8; ++j) {
            int nt = nh * 8 + j;
            bf16x8 b = *(const bf16x8*)(WoP + (long)(((nt * 2 + ks) << 6) + l) * 8);
            acc[j] = __builtin_amdgcn_mfma_f32_16x16x32_bf16(af[ks], b, acc[j], 0, 0, 0);
        }

    float bov[8], g1v[8], be1v[8];
#pragma unroll
    for (int j = 0; j < 8; ++j) {
        int col = (nh * 8 + j) * 16 + l15;
        bov[j] = bo[col]; g1v[j] = g1[col]; be1v[j] = be1[col];
    }

    float xv[4][8];
#pragma unroll
    for (int rg = 0; rg < 4; ++rg) {
        long grow = row0 + ri * 16 + lh * 4 + rg;
        float s = 0.f, q = 0.f;
#pragma unroll
        for (int j = 0; j < 8; ++j) {
            float v = acc[j][rg] + bov[j] +
                      __bfloat162float(Xpb[grow * CC + (nh * 8 + j) * 16 + l15]);
            xv[rg][j] = v; s += v; q += v * v;
        }
#pragma unroll
        for (int o = 8; o > 0; o >>= 1) { s += __shfl_xor(s, o); q += __shfl_xor(q, o); }
        if (l15 == 0) {
            int rl = ri * 16 + lh * 4 + rg;
            red[nh][rl][0] = s; red[nh][rl][1] = q;
        }
    }
    __syncthreads();
    if (t < 32) {
        float S = red[0][t][0] + red[1][t][0];
        float Q = red[0][t][1] + red[1][t][1];
        float mu = S * (1.f / CC);
        float var = Q * (1.f / CC) - mu * mu;
        mrs[t][0] = mu; mrs[t][1] = rsqrtf(var + EPSF);
    }
    __syncthreads();
#pragma unroll
    for (int rg = 0; rg < 4; ++rg) {
        int rl = ri * 16 + lh * 4 + rg;
        long grow = row0 + rl;
        float mu = mrs[rl][0], rs = mrs[rl][1];
#pragma unroll
        for (int j = 0; j < 8; ++j) {
            int col = (nh * 8 + j) * 16 + l15;
            float vout = (xv[rg][j] - mu) * rs * g1v[j] + be1v[j];
            Xnb[grow * CC + col] = __float2bfloat16(vout);
            __hip_fp8_e4m3 q8(vout);
            Xn8[grow * CC + col] = q8.__x;
        }
    }
}

// ---------------------------------------------------------------------------
// GEMM1 MX-fp8: H = relu(Xn8 @ W1 + b1), 128x128 tile, 4 waves, K=256 done
// in 2 x mfma_scale_f32_16x16x128_f8f6f4 (unit scales). A = fp8 X from
// swizzled LDS; B = MX-frag-packed W1 streamed from L2. 32 MFMA/wave total.
template<int GRL2, int CTL2>
__global__ __launch_bounds__(256) void k_gemm1mx(
    const unsigned char* __restrict__ X8,    // [32768][256] fp8 e4m3
    const unsigned char* __restrict__ W1P8,  // MX frag pack, 256 KB
    const float* __restrict__ bias,          // b1 [1024]
    __hip_bfloat16* __restrict__ H) {        // [32768][1024]
    __shared__ unsigned char Xs[128 * 256];  // 32 KB; 16B-chunk XOR swizzle

    const int t = threadIdx.x, w = t >> 6, l = t & 63;
    const int l15 = l & 15, lh = l >> 4;
    const int bid = blockIdx.x;
    const int wi = bid & ((1 << (GRL2 + CTL2)) - 1);
    const int rt = ((bid >> (GRL2 + CTL2)) << GRL2) | (wi & ((1 << GRL2) - 1));
    const int ct = wi >> GRL2;
    const int row0 = rt * 128, n0 = ct * 128;
    const int wr = w & 1, wc = w >> 1;

    // stage X tile: 128 rows x 16 chunks of 16B, swizzle chunk ^= row&7
    for (int i = t; i < 2048; i += 256) {
        int r = i >> 4, c = i & 15;
        int pc = c ^ (r & 7);
        *(int4*)(Xs + r * 256 + pc * 16) =
            *(const int4*)(X8 + (long)(row0 + r) * 256 + c * 16);
    }
    __syncthreads();

    // A-frags [f][kb]: row = wr*64 + f*16 + l15; k = kb*128 + lh*32 + e
    i32x8 afr[4][2];
#pragma unroll
    for (int f = 0; f < 4; ++f) {
        int row = wr * 64 + f * 16 + l15;
        int sw = row & 7;
#pragma unroll
        for (int kb = 0; kb < 2; ++kb) {
            int c0 = kb * 8 + lh * 2;
            int4 lo = *(const int4*)(Xs + row * 256 + (c0 ^ sw) * 16);
            int4 hi = *(const int4*)(Xs + row * 256 + ((c0 + 1) ^ sw) * 16);
            afr[f][kb][0] = lo.x; afr[f][kb][1] = lo.y;
            afr[f][kb][2] = lo.z; afr[f][kb][3] = lo.w;
            afr[f][kb][4] = hi.x; afr[f][kb][5] = hi.y;
            afr[f][kb][6] = hi.z; afr[f][kb][7] = hi.w;
        }
    }

    f32x4 acc[4][4];
#pragma unroll
    for (int i = 0; i < 4; ++i)
#pragma unroll
        for (int j = 0; j < 4; ++j) acc[i][j] = (f32x4)(0.f);

#pragma unroll
    for (int kb = 0; kb < 2; ++kb)
#pragma unroll
        for (int nf = 0; nf < 4; ++nf) {
            int nt = (n0 >> 4) + wc * 4 + nf;
            const unsigned char* bp = W1P8 + ((long)((nt * 2 + kb) * 64 + l)) * 32;
            int4 lo = *(const int4*)(bp);
            int4 hi = *(const int4*)(bp + 16);
            i32x8 bfr;
            bfr[0] = lo.x; bfr[1] = lo.y; bfr[2] = lo.z; bfr[3] = lo.w;
            bfr[4] = hi.x; bfr[5] = hi.y; bfr[6] = hi.z; bfr[7] = hi.w;
#pragma unroll
            for (int f = 0; f < 4; ++f)
                acc[f][nf] = __builtin_amdgcn_mfma_scale_f32_16x16x128_f8f6f4(
                    afr[f][kb], bfr, acc[f][nf], 0, 0, 0, 127, 0, 127);
        }

#pragma unroll
    for (int nf = 0; nf < 4; ++nf) {
        int col = n0 + wc * 64 + nf * 16 + l15;
        float bv = bias[col];
#pragma unroll
        for (int f = 0; f < 4; ++f)
#pragma unroll
            for (int rg = 0; rg < 4; ++rg) {
                int row = wr * 64 + f * 16 + lh * 4 + rg;
                long gi = (long)(row0 + row) * 1024 + col;
                H[gi] = __float2bfloat16(fmaxf(acc[f][nf][rg] + bv, 0.f));
            }
    }
}

// ---------------------------------------------------------------------------
// GEMM2 + residual + LN2 fused: 64 rows x 256 cols, 512 thr, 8 waves,
// K=1024, BK=64 (16 steps). Depth-2 DMA LDS, counted vmcnt(5).
__global__ __launch_bounds__(512) void k_gemm2ln(
    const __hip_bfloat16* __restrict__ A,      // H [32768][1024]
    const __hip_bfloat16* __restrict__ BT,     // W2T [256][1024]
    const float* __restrict__ b2,
    const __hip_bfloat16* __restrict__ Res,    // Xn bf16 [32768][256]
    const float* __restrict__ g2, const float* __restrict__ be2,
    float* __restrict__ out) {
    __shared__ short As[2][4096];       // 2 x 8 KB  (64 r x 128 B)
    __shared__ short Bs[2][16384];      // 2 x 32 KB (256 r x 128 B)
    float* red = (float*)As;            // [4][64][2], aliased after K-loop
    float* mrs = (float*)As + 512;      // [64][2]

    const int t = threadIdx.x, w = t >> 6, l = t & 63;
    const int l15 = l & 15, lh = l >> 4;
    const int wr = w >> 2, wc = w & 3;
    const int row0 = blockIdx.x * 64;

    const __hip_bfloat16* gA;
    { int r, c; inv_swz128(t * 16, r, c); gA = A + (long)(row0 + r) * 1024 + c * 8; }
    const __hip_bfloat16* gB[4];
#pragma unroll
    for (int j = 0; j < 4; ++j) {
        int r, c;
        inv_swz128(j * 8192 + t * 16, r, c);
        gB[j] = BT + (long)r * 1024 + c * 8;
    }
    char* ldsA = (char*)As + w * 1024;
    char* ldsB = (char*)Bs + w * 1024;

    int offA[2][2], offB[4][2];
#pragma unroll
    for (int f = 0; f < 2; ++f) {
        int rowA = wr * 32 + f * 16 + l15;
        int sw = (rowA & 7) << 4;
#pragma unroll
        for (int kk = 0; kk < 2; ++kk)
            offA[f][kk] = rowA * 128 + ((kk * 64 + lh * 16) ^ sw);
    }
#pragma unroll
    for (int f = 0; f < 4; ++f) {
        int rowB = wc * 64 + f * 16 + l15;
        int sw = (rowB & 7) << 4;
#pragma unroll
        for (int kk = 0; kk < 2; ++kk)
            offB[f][kk] = rowB * 128 + ((kk * 64 + lh * 16) ^ sw);
    }

    f32x4 acc[2][4];
#pragma unroll
    for (int i = 0; i < 2; ++i)
#pragma unroll
        for (int j = 0; j < 4; ++j) acc[i][j] = (f32x4)(0.f);

#pragma unroll
    for (int n = 0; n < 2; ++n) {
        gl_lds16(gA + n * 64, ldsA + n * 8192);
#pragma unroll
        for (int j = 0; j < 4; ++j)
            gl_lds16(gB[j] + n * 64, ldsB + n * 32768 + j * 8192);
    }

#pragma unroll 1
    for (int ks = 0; ks < 16; ++ks) {
        if (ks + 1 < 16) { WAIT_VM(5); } else { WAIT_VM(0); }
        const char* as = (const char*)As + (ks & 1) * 8192;
        const char* bs = (const char*)Bs + (ks & 1) * 32768;
        bf16x8 afr[2][2], bfr[4][2];
#pragma unroll
        for (int f = 0; f < 2; ++f)
#pragma unroll
            for (int kk = 0; kk < 2; ++kk)
                afr[f][kk] = *(const bf16x8*)(as + offA[f][kk]);
#pragma unroll
        for (int f = 0; f < 4; ++f)
#pragma unroll
            for (int kk = 0; kk < 2; ++kk)
                bfr[f][kk] = *(const bf16x8*)(bs + offB[f][kk]);
        asm volatile("s_waitcnt lgkmcnt(0)" ::: "memory");
        __builtin_amdgcn_s_barrier();
        __builtin_amdgcn_sched_barrier(0);
        if (ks + 2 < 16) {
            gl_lds16(gA + (ks + 2) * 64, ldsA + (ks & 1) * 8192);
#pragma unroll
            for (int j = 0; j < 4; ++j)
                gl_lds16(gB[j] + (ks + 2) * 64, ldsB + (ks & 1) * 32768 + j * 8192);
        }
#pragma unroll
        for (int kk = 0; kk < 2; ++kk)
#pragma unroll
            for (int fr = 0; fr < 2; ++fr)
#pragma unroll
                for (int fc = 0; fc < 4; ++fc)
                    acc[fr][fc] = __builtin_amdgcn_mfma_f32_16x16x32_bf16(
                        afr[fr][kk], bfr[fc][kk], acc[fr][fc], 0, 0, 0);
    }

    float b2v[4], g2v[4], be2v[4];
#pragma unroll
    for (int fc = 0; fc < 4; ++fc) {
        int col = wc * 64 + fc * 16 + l15;
        b2v[fc] = b2[col]; g2v[fc] = g2[col]; be2v[fc] = be2[col];
    }
    __syncthreads();
#pragma unroll
    for (int fr = 0; fr < 2; ++fr)
#pragma unroll
        for (int rg = 0; rg < 4; ++rg) {
            int row = wr * 32 + fr * 16 + lh * 4 + rg;
            float s = 0.f, q = 0.f;
#pragma unroll
            for (int fc = 0; fc < 4; ++fc) {
                long gi = (long)(row0 + row) * CC + wc * 64 + fc * 16 + l15;
                float v = acc[fr][fc][rg] + b2v[fc] + __bfloat162float(Res[gi]);
                acc[fr][fc][rg] = v;
                s += v; q += v * v;
            }
#pragma unroll
            for (int o = 8; o > 0; o >>= 1) {
                s += __shfl_xor(s, o); q += __shfl_xor(q, o);
            }
            if (l15 == 0) {
                red[(wc * 64 + row) * 2 + 0] = s;
                red[(wc * 64 + row) * 2 + 1] = q;
            }
        }
    __syncthreads();
    if (t < 64) {
        float S = 0.f, Q = 0.f;
#pragma unroll
        for (int ww = 0; ww < 4; ++ww) {
            S += red[(ww * 64 + t) * 2 + 0];
            Q += red[(ww * 64 + t) * 2 + 1];
        }
        float mu = S * (1.f / CC);
        float var = Q * (1.f / CC) - mu * mu;
        mrs[t * 2 + 0] = mu; mrs[t * 2 + 1] = rsqrtf(var + EPSF);
    }
    __syncthreads();
#pragma unroll
    for (int fr = 0; fr < 2; ++fr)
#pragma unroll
        for (int rg = 0; rg < 4; ++rg) {
            int row = wr * 32 + fr * 16 + lh * 4 + rg;
            float mu = mrs[row * 2 + 0], rs = mrs[row * 2 + 1];
#pragma unroll
            for (int fc = 0; fc < 4; ++fc) {
                long gi = (long)(row0 + row) * CC + wc * 64 + fc * 16 + l15;
                out[gi] = (acc[fr][fc][rg] - mu) * rs * g2v[fc] + be2v[fc];
            }
        }
}

// ---------------------------------------------------------------------------
extern "C" void kernel_launch(void* const* d_in, const int* in_sizes, int n_in,
                              void* d_out, int out_size, void* d_ws, size_t ws_size,
                              hipStream_t stream) {
    const float* X   = (const float*)d_in[0];
    const int*   sel = (const int*)d_in[1];
    const float* pe  = (const float*)d_in[3];
    const float* Wq  = (const float*)d_in[4];
    const float* bq  = (const float*)d_in[5];
    const float* Wk  = (const float*)d_in[6];
    const float* bk  = (const float*)d_in[7];
    const float* Wv  = (const float*)d_in[8];
    const float* bv  = (const float*)d_in[9];
    const float* Wo  = (const float*)d_in[10];
    const float* bo  = (const float*)d_in[11];
    const float* W1  = (const float*)d_in[12];
    const float* b1  = (const float*)d_in[13];
    const float* W2  = (const float*)d_in[14];
    const float* b2  = (const float*)d_in[15];
    const float* g1  = (const float*)d_in[16];
    const float* be1 = (const float*)d_in[17];
    const float* g2  = (const float*)d_in[18];
    const float* be2 = (const float*)d_in[19];

    float* out = (float*)d_out;
    char*  ws  = (char*)d_ws;       // ws_size ~= 256 MiB

    __hip_bfloat16* Xpb = (__hip_bfloat16*)(ws);                  // 16 MB (Xp->Xn in place)
    __hip_bfloat16* Qb  = (__hip_bfloat16*)(ws + (16 << 20));     // 4 MB
    __hip_bfloat16* Kb  = (__hip_bfloat16*)(ws + (20 << 20));     // 4 MB
    __hip_bfloat16* Vb  = (__hip_bfloat16*)(ws + (24 << 20));     // 4 MB
    __hip_bfloat16* ctxb= (__hip_bfloat16*)(ws + (28 << 20));     // 4 MB
    __hip_bfloat16* H   = (__hip_bfloat16*)(ws + (16 << 20));     // 64 MB (reuses QKV/ctx)
    unsigned char*  Xn8 = (unsigned char*)(ws + (88 << 20));      // 8 MB fp8 Xn
    __hip_bfloat16* WqP = (__hip_bfloat16*)(ws + (96 << 20));     // 32 KB
    __hip_bfloat16* WkP = WqP + 16384;
    __hip_bfloat16* WvP = WkP + 16384;
    __hip_bfloat16* WoP = WvP + 16384;                            // 32 KB
    unsigned char*  W1P8= (unsigned char*)(WoP + 16384);          // 256 KB MX fp8
    __hip_bfloat16* W2T = (__hip_bfloat16*)(W1P8 + 262144);       // 512 KB [256][1024]
    float* attn_out = out + (long)ROWS * CC;

    k_prep<<<768, 256, 0, stream>>>(Wq, Wk, Wv, Wo, W1, W2,
                                    WqP, WkP, WvP, WoP, W1P8, W2T);

    k_qkv<<<ROWS / 32, 256, 0, stream>>>((const float4*)X, (const float4*)pe,
                                         WqP, WkP, WvP, bq, bk, bv,
                                         Xpb, Qb, Kb, Vb);

    k_attn<<<ROWS / 4, 256, 0, stream>>>(Qb, Kb, Vb, sel, ctxb, attn_out);

    k_projln<<<ROWS / 32, 256, 0, stream>>>(ctxb, WoP, bo, g1, be1, Xpb, Xpb, Xn8);

    // FFN: H = relu(Xn @ W1 + b1)  [MX-fp8, 128x128 tiles, 2048 blocks]
    k_gemm1mx<2, 3><<<2048, 256, 0, stream>>>(Xn8, W1P8, b1, H);
    // out = LN(H @ W2 + b2 + Xn) * g2 + be2  [64x256 tiles, BK=64, 512 blocks]
    k_gemm2ln<<<512, 512, 0, stream>>>(H, W2T, b2, Xpb, g2, be2, out);
}